// Round 3
// baseline (1514.860 us; speedup 1.0000x reference)
//
#include <hip/hip_runtime.h>
#include <hip/hip_bf16.h>

// GATConv with edge features, MI355X. Round 3: bf16 MFMA edge GEMM + CSR
// one-writer aggregation (no atomics).
//
// R2 post-mortem: edge kernel 640us = 237us fp32-FMA floor (VALUBusy 37%)
// + ~400us memory/latency, WRITE_SIZE 575MB (11x ideal; 4B atomics dirty
// 64B lines). Fix both: MFMA (26GF -> ~12us) and per-dst wave ownership
// (plain stores, 51MB writes; nh loaded once per dst).
//
// Algebra: m = src_proj[src] + edge_feat @ W_bot ; softmax max-free:
//   rst = sum(ex*m)/sum(ex) + bias,  ex = exp(leaky(m + nh[dst]))

#define F 128
#define C 128
#define NEG 0.2f
#define NN 50000
#define EE 800000

typedef short short8 __attribute__((ext_vector_type(8)));
typedef float f32x4  __attribute__((ext_vector_type(4)));

// W_bot^T in bf16, [n][k] layout (B^T rows = contiguous k) — 32 KB module global
__device__ ushort g_wt[C * F];

__device__ __forceinline__ ushort f2bf(float x) {
    __hip_bfloat16 h = __float2bfloat16(x);
    return *(ushort*)&h;
}

// ---------------- prep: g_wt[n][k] = bf16(W_src[128+k][n])
__global__ __launch_bounds__(256) void prep_wt_kernel(const float* __restrict__ W_src) {
    int idx = blockIdx.x * 256 + threadIdx.x;   // 16384 total
    int n = idx >> 7, k = idx & 127;
    g_wt[idx] = f2bf(W_src[(size_t)(128 + k) * C + n]);
}

__device__ __forceinline__ void fma4(float4& a, float s, const float4 w) {
    a.x += s * w.x; a.y += s * w.y; a.z += s * w.z; a.w += s * w.w;
}

// ---------------- node projection (fp32 VALU, cheap): src_proj and nh
__global__ __launch_bounds__(256) void node_proj_kernel(
    const float* __restrict__ src_feat, const float* __restrict__ dst_feat,
    const float* __restrict__ W_src, const float* __restrict__ W_dst,
    float* __restrict__ src_proj, float* __restrict__ nh)
{
    const float* in; const float* W; float* out;
    if (blockIdx.y == 0) { in = src_feat; W = W_src; out = src_proj; }
    else                 { in = dst_feat; W = W_dst; out = nh; }

    __shared__ float4 xs[8 * 32];
    const int t  = threadIdx.x;
    const int nb = blockIdx.x * 8;
    {
        int row = t >> 5, col = t & 31;
        xs[t] = ((const float4*)(in + (size_t)(nb + row) * F))[col];
    }
    __syncthreads();

    const int jq = t & 31;
    const int ng = t >> 5;
    float4 acc = make_float4(0.f, 0.f, 0.f, 0.f);
    const float4* W4 = (const float4*)W;

    #pragma unroll 4
    for (int k4 = 0; k4 < 32; ++k4) {
        float4 xv = xs[ng * 32 + k4];
        float4 w0 = W4[(4 * k4 + 0) * 32 + jq];
        float4 w1 = W4[(4 * k4 + 1) * 32 + jq];
        float4 w2 = W4[(4 * k4 + 2) * 32 + jq];
        float4 w3 = W4[(4 * k4 + 3) * 32 + jq];
        fma4(acc, xv.x, w0); fma4(acc, xv.y, w1);
        fma4(acc, xv.z, w2); fma4(acc, xv.w, w3);
    }
    ((float4*)(out + (size_t)(nb + ng) * C))[jq] = acc;
}

// ---------------- sort-by-dst machinery ----------------
__global__ __launch_bounds__(256) void hist_kernel(
    const int* __restrict__ dst_idx, int* __restrict__ deg)
{
    int e = blockIdx.x * 256 + threadIdx.x;
    if (e < EE) atomicAdd(&deg[dst_idx[e]], 1);
}

__global__ __launch_bounds__(1024) void scan_kernel(
    const int* __restrict__ deg, int* __restrict__ cursor)
{
    __shared__ int ssum[1024];
    const int t = threadIdx.x;
    const int chunk = (NN + 1023) / 1024;
    int lo = t * chunk, hi = lo + chunk; if (hi > NN) hi = NN; if (lo > NN) lo = NN;
    int s = 0;
    for (int i = lo; i < hi; ++i) s += deg[i];
    ssum[t] = s;
    __syncthreads();
    for (int d = 1; d < 1024; d <<= 1) {
        int v = (t >= d) ? ssum[t - d] : 0;
        __syncthreads();
        ssum[t] += v;
        __syncthreads();
    }
    int run = ssum[t] - s;
    for (int i = lo; i < hi; ++i) { cursor[i] = run; run += deg[i]; }
}

__global__ __launch_bounds__(256) void scatter_kernel(
    const int* __restrict__ dst_idx, int* __restrict__ cursor, int* __restrict__ elist)
{
    int e = blockIdx.x * 256 + threadIdx.x;
    if (e < EE) {
        int p = atomicAdd(&cursor[dst_idx[e]], 1);
        elist[p] = e;
    }
    // after this kernel cursor[d] = segment END; start = cursor[d] - deg[d]
}

// ---------------- CSR edge kernel: one wave per (dst, channel-half)
// block = 256 = 4 waves; global wave gw -> dst = gw>>1, half = gw&1.
// Per pass: stage 16 edge rows (bf16, wave-private LDS), 16 MFMAs
// (4 ntile x 4 kstep), epilogue exp + per-lane accumulate. No barriers,
// no atomics; final butterfly + plain stores.
__global__ __launch_bounds__(256) void csr_edge_kernel(
    const float* __restrict__ edge_feat,
    const float* __restrict__ src_proj, const float* __restrict__ nh,
    const int* __restrict__ src_idx, const int* __restrict__ elist,
    const int* __restrict__ deg, const int* __restrict__ cursor,
    float* __restrict__ num, float* __restrict__ den)
{
    // per-wave staging: 16 rows x (128+8) bf16, +8 pad breaks bank conflicts
    __shared__ __align__(16) ushort stage[4][16 * 136];
    __shared__ int sdix[4][16];   // src index per staged row
    __shared__ int seid[4][16];   // edge id per staged row

    const int t    = threadIdx.x;
    const int w    = t >> 6;
    const int l    = t & 63;
    const int gw   = blockIdx.x * 4 + w;
    const int dst  = gw >> 1;
    const int half = gw & 1;
    if (dst >= NN) return;

    const int dg    = deg[dst];
    const int start = cursor[dst] - dg;
    const int lo    = l & 15;
    const int q     = l >> 4;

    // B fragments: W_bot^T bf16, registers for whole kernel (4 ntiles x 4 ksteps)
    short8 bfrag[4][4];
    #pragma unroll
    for (int tt = 0; tt < 4; ++tt) {
        int n = half * 64 + tt * 16 + lo;
        #pragma unroll
        for (int s = 0; s < 4; ++s)
            bfrag[tt][s] = *(const short8*)&g_wt[n * F + s * 32 + q * 8];
    }
    // nh[dst] once per wave
    float nv[4];
    #pragma unroll
    for (int tt = 0; tt < 4; ++tt)
        nv[tt] = nh[(size_t)dst * C + half * 64 + tt * 16 + lo];

    float nsum[4] = {0.f, 0.f, 0.f, 0.f};
    float dsum[4] = {0.f, 0.f, 0.f, 0.f};
    ushort* st = stage[w];

    const int passes = (dg + 15) >> 4;
    for (int p = 0; p < passes; ++p) {
        const int base = p * 16;

        // stage per-row edge id + src id (lanes 0..15)
        if (l < 16) {
            int el = base + l;
            int e  = (el < dg) ? elist[start + el] : 0;
            seid[w][l] = e;
            sdix[w][l] = (el < dg) ? src_idx[e] : 0;
        }
        // stage 16 rows as bf16 (512 float4 loads per wave-pass, 8 per lane)
        #pragma unroll
        for (int i = 0; i < 8; ++i) {
            int qq  = l + 64 * i;          // 0..511
            int row = qq >> 5, c4 = qq & 31;
            int el  = base + row;
            float4 v = make_float4(0.f, 0.f, 0.f, 0.f);
            if (el < dg)
                v = ((const float4*)edge_feat)[(size_t)seid[w][row] * 32 + c4];
            ushort4 b;
            b.x = f2bf(v.x); b.y = f2bf(v.y); b.z = f2bf(v.z); b.w = f2bf(v.w);
            *(ushort4*)&st[row * 136 + c4 * 4] = b;
        }
        // A fragments: lane -> edge row lo, k = s*32 + q*8 .. +8 (ds_read_b128)
        short8 af[4];
        #pragma unroll
        for (int s = 0; s < 4; ++s)
            af[s] = *(const short8*)&st[lo * 136 + s * 32 + q * 8];

        f32x4 acc[4];
        #pragma unroll
        for (int tt = 0; tt < 4; ++tt) acc[tt] = (f32x4){0.f, 0.f, 0.f, 0.f};
        #pragma unroll
        for (int tt = 0; tt < 4; ++tt)
            #pragma unroll
            for (int s = 0; s < 4; ++s)
                acc[tt] = __builtin_amdgcn_mfma_f32_16x16x32_bf16(
                              af[s], bfrag[tt][s], acc[tt], 0, 0, 0);

        // epilogue: D row = q*4+r = edge within pass, col = channel lo
        #pragma unroll
        for (int tt = 0; tt < 4; ++tt) {
            int ch = half * 64 + tt * 16 + lo;
            #pragma unroll
            for (int r = 0; r < 4; ++r) {
                int erow = q * 4 + r;
                int el   = base + erow;
                if (el < dg) {
                    int   si = sdix[w][erow];
                    float m  = acc[tt][r] + src_proj[(size_t)si * C + ch];
                    float s  = m + nv[tt];
                    s = s > 0.f ? s : NEG * s;
                    float ex = __expf(s);
                    nsum[tt] += ex * m;
                    dsum[tt] += ex;
                }
            }
        }
    }

    // butterfly over the 4 lane-groups, then plain stores (one writer per dst)
    #pragma unroll
    for (int tt = 0; tt < 4; ++tt) {
        float n0 = nsum[tt], d0 = dsum[tt];
        n0 += __shfl_xor(n0, 16); n0 += __shfl_xor(n0, 32);
        d0 += __shfl_xor(d0, 16); d0 += __shfl_xor(d0, 32);
        int ch = half * 64 + tt * 16 + lo;
        if (q == 0)      num[(size_t)dst * C + ch] = n0;
        else if (q == 1) den[(size_t)dst * C + ch] = d0;
    }
}

// ---------------- finalize: out = num/den + bias
__global__ __launch_bounds__(256) void finalize_kernel(
    const float* __restrict__ num, const float* __restrict__ den,
    const float* __restrict__ bias, float* __restrict__ out)
{
    int i = blockIdx.x * 256 + threadIdx.x;
    float4 n = ((const float4*)num)[i];
    float4 d = ((const float4*)den)[i];
    float4 b = ((const float4*)bias)[i & 31];
    float4 r;
    r.x = (d.x != 0.f ? n.x / d.x : 0.f) + b.x;
    r.y = (d.y != 0.f ? n.y / d.y : 0.f) + b.y;
    r.z = (d.z != 0.f ? n.z / d.z : 0.f) + b.z;
    r.w = (d.w != 0.f ? n.w / d.w : 0.f) + b.w;
    ((float4*)out)[i] = r;
}

extern "C" void kernel_launch(void* const* d_in, const int* in_sizes, int n_in,
                              void* d_out, int out_size, void* d_ws, size_t ws_size,
                              hipStream_t stream) {
    const float* src_feat  = (const float*)d_in[0];
    const float* dst_feat  = (const float*)d_in[1];
    const float* edge_feat = (const float*)d_in[2];
    const float* W_src     = (const float*)d_in[3];   // [256][128]
    const float* W_dst     = (const float*)d_in[4];   // [128][128]
    const float* bias      = (const float*)d_in[5];
    const int*   src_idx   = (const int*)d_in[6];
    const int*   dst_idx   = (const int*)d_in[7];
    float* out = (float*)d_out;

    const size_t NODEF = (size_t)NN * C;

    float* ws       = (float*)d_ws;
    float* src_proj = ws;                             // 25.6 MB
    float* nh       = ws + NODEF;                     // 25.6 MB
    float* den      = ws + 2 * NODEF;                 // 25.6 MB
    int*   deg      = (int*)(ws + 3 * NODEF);         // 200 KB
    int*   cursor   = deg + NN;                       // 200 KB
    int*   elist    = cursor + NN;                    // 3.2 MB

    float* num = out;   // written by CSR kernel (full coverage), finalized in place

    hipMemsetAsync(deg, 0, NN * sizeof(int), stream);

    prep_wt_kernel<<<64, 256, 0, stream>>>(W_src);
    hist_kernel<<<(EE + 255) / 256, 256, 0, stream>>>(dst_idx, deg);
    scan_kernel<<<1, 1024, 0, stream>>>(deg, cursor);
    scatter_kernel<<<(EE + 255) / 256, 256, 0, stream>>>(dst_idx, cursor, elist);

    node_proj_kernel<<<dim3(NN / 8, 2), 256, 0, stream>>>(
        src_feat, dst_feat, W_src, W_dst, src_proj, nh);

    csr_edge_kernel<<<NN / 2, 256, 0, stream>>>(
        edge_feat, src_proj, nh, src_idx, elist, deg, cursor, num, den);

    finalize_kernel<<<NODEF / 4 / 256, 256, 0, stream>>>(num, den, bias, out);
}